// Round 1
// baseline (365.289 us; speedup 1.0000x reference)
//
#include <hip/hip_runtime.h>
#include <math.h>

#define T_TOKENS 4096
#define HIDDEN   2048
#define N_EXPERTS 8
#define N_ROWS   (N_EXPERTS * T_TOKENS)   // 32768 rows of router_indices
#define ROW_F4   (HIDDEN / 4)             // 512 float4 per row

// Fused launch geometry: 2048 blocks, all co-resident (0 LDS, low VGPR).
// 1 in 8 blocks is a "router" block -> 256 router blocks x 16 tokens = 4096.
// 7 in 8 blocks are "fill" blocks  -> 1792 blocks stream the 268 MB fill.
// Rationale (R3): the two prior kernels ran serially; router is L1/latency-
// bound, fill is HBM-write-bound -> fusing overlaps them. Dropping the 64 KB
// LDS W-stage (W is 64 KB read-only, L1/L2-resident) removes the 2-blocks/CU
// occupancy cap so fill waves co-reside with router waves on every CU.
#define NBLOCKS     2048
#define FILL_BLOCKS 1792
#define FILL_WAVES  (FILL_BLOCKS * 4)     // 7168

__global__ __launch_bounds__(256) void fused_router_fill(
    const float* __restrict__ h, const float* __restrict__ w,
    float* __restrict__ out0, float* __restrict__ out1, float* __restrict__ out2)
{
    const int bid  = blockIdx.x;
    const int wave = threadIdx.x >> 6;
    const int lane = threadIdx.x & 63;

    if ((bid & 7) == 0) {
        // ------------------- router role: 16 tokens per block -------------------
        const int rb = bid >> 3;                 // 0..255
        const int t0 = rb * 16 + wave * 4;       // 4 tokens per wave

        const float4* h4 = (const float4*)h;
        const float4* w4 = (const float4*)w;

        float acc[4][N_EXPERTS];
        #pragma unroll
        for (int t = 0; t < 4; t++)
            #pragma unroll
            for (int e = 0; e < N_EXPERTS; e++) acc[t][e] = 0.f;

        // Lane+k tile the 512 float4 of a row: pos = k*64 + lane.
        // Per k: 4 h-loads (streaming, HBM) + 8 W-loads (hot in L1/L2),
        // 32 float4 FMAs. W traffic per token = 16 KB (was 64 KB).
        #pragma unroll
        for (int k = 0; k < 8; k++) {
            float4 hv[4];
            #pragma unroll
            for (int t = 0; t < 4; t++)
                hv[t] = h4[(size_t)(t0 + t) * ROW_F4 + k * 64 + lane];
            #pragma unroll
            for (int e = 0; e < N_EXPERTS; e++) {
                float4 wv = w4[e * ROW_F4 + k * 64 + lane];
                #pragma unroll
                for (int t = 0; t < 4; t++)
                    acc[t][e] += hv[t].x * wv.x + hv[t].y * wv.y
                               + hv[t].z * wv.z + hv[t].w * wv.w;
            }
        }

        // 64-lane shuffle reduction for all 32 accumulators
        #pragma unroll
        for (int t = 0; t < 4; t++)
            #pragma unroll
            for (int e = 0; e < N_EXPERTS; e++)
                #pragma unroll
                for (int off = 32; off > 0; off >>= 1)
                    acc[t][e] += __shfl_down(acc[t][e], off, 64);

        if (lane == 0) {
            #pragma unroll
            for (int t = 0; t < 4; t++) {
                const int tok = t0 + t;
                // top-2 of 8; strict > keeps first index on ties (== lax.top_k)
                int i1 = 0; float v1 = acc[t][0];
                #pragma unroll
                for (int e = 1; e < N_EXPERTS; e++)
                    if (acc[t][e] > v1) { v1 = acc[t][e]; i1 = e; }
                int i2 = -1; float v2 = -INFINITY;
                #pragma unroll
                for (int e = 0; e < N_EXPERTS; e++)
                    if (e != i1 && acc[t][e] > v2) { v2 = acc[t][e]; i2 = e; }

                float s1 = 1.f / (1.f + expf(-v1));
                float s2 = 1.f / (1.f + expf(-v2));

                #pragma unroll
                for (int e = 0; e < N_EXPERTS; e++) {
                    float val = (e == i1) ? s1 : ((e == i2) ? s2 : 0.f);
                    out0[e * T_TOKENS + tok] = val;
                    out2[e * T_TOKENS + tok] = val;
                }
            }
        }
    } else {
        // ------------------- fill role: stream router_indices -------------------
        // Row er = e*T + t holds constant value t = er & 4095 across H=2048.
        // One wave covers a row as 8 unrolled 1 KB wave-wide dwordx4 stores;
        // v is computed once per 8 KB row. Plain stores (NT was 6x slower, R2).
        const int fb    = (bid >> 3) * 7 + (bid & 7) - 1;  // 0..1791
        const int fwave = fb * 4 + wave;                   // 0..7167
        float4* o4 = (float4*)out1;

        for (int r = fwave; r < N_ROWS; r += FILL_WAVES) {
            float v = (float)(r & (T_TOKENS - 1));
            float4 vv = make_float4(v, v, v, v);
            float4* rowp = o4 + (size_t)r * ROW_F4;
            #pragma unroll
            for (int j = 0; j < 8; j++)
                rowp[j * 64 + lane] = vv;
        }
    }
}

extern "C" void kernel_launch(void* const* d_in, const int* in_sizes, int n_in,
                              void* d_out, int out_size, void* d_ws, size_t ws_size,
                              hipStream_t stream) {
    const float* h = (const float*)d_in[0];   // [4096, 2048] f32
    const float* w = (const float*)d_in[1];   // [8, 2048] f32
    // d_in[2] = top_k (always 2 for this problem)

    float* out  = (float*)d_out;
    float* out0 = out;                                            // router_scores [8,4096]
    float* out1 = out + N_EXPERTS * T_TOKENS;                     // router_indices [32768,2048]
    float* out2 = out1 + (size_t)N_EXPERTS * T_TOKENS * HIDDEN;   // router_probs [32768,1]

    hipLaunchKernelGGL(fused_router_fill, dim3(NBLOCKS), dim3(256), 0, stream,
                       h, w, out0, out1, out2);
}

// Round 2
// 332.607 us; speedup vs baseline: 1.0983x; 1.0983x over previous
//
#include <hip/hip_runtime.h>
#include <math.h>

#define T_TOKENS 4096
#define HIDDEN   2048
#define N_EXPERTS 8
#define N_ROWS   (N_EXPERTS * T_TOKENS)   // 32768 rows of router_indices
#define ROW_F4   (HIDDEN / 4)             // 512 float4 per row

// Fused launch geometry: 2048 blocks, 0 LDS, all co-resident (8 blocks/CU).
// R4 FIX: router role was (bid & 7)==0, but workgroup->XCD assignment is
// round-robin (XCD = bid % 8, learn_hip m09 + swizzle idiom) -> ALL router
// blocks piled onto XCD 0; 7/8 of the chip idled during a long router tail
// (counters: 176 us, 1.6 TB/s avg, VALUBusy 2.4%, Occupancy 16%).
// Now router = bid < 256: bids round-robin XCD then CU, so bids 0..255 land
// exactly 1 per CU -> every CU gets 1 router block + 7 fill blocks.
#define NBLOCKS       2048
#define ROUTER_BLOCKS 256
#define FILL_BLOCKS   (NBLOCKS - ROUTER_BLOCKS)   // 1792
#define FILL_WAVES    (FILL_BLOCKS * 4)           // 7168

__global__ __launch_bounds__(256) void fused_router_fill(
    const float* __restrict__ h, const float* __restrict__ w,
    float* __restrict__ out0, float* __restrict__ out1, float* __restrict__ out2)
{
    const int bid  = blockIdx.x;
    const int wave = threadIdx.x >> 6;
    const int lane = threadIdx.x & 63;

    if (bid < ROUTER_BLOCKS) {
        // ------------------- router role: 16 tokens per block -------------------
        const int t0 = bid * 16 + wave * 4;      // 4 tokens per wave

        const float4* h4 = (const float4*)h;
        const float4* w4 = (const float4*)w;

        float acc[4][N_EXPERTS];
        #pragma unroll
        for (int t = 0; t < 4; t++)
            #pragma unroll
            for (int e = 0; e < N_EXPERTS; e++) acc[t][e] = 0.f;

        // Lane+k tile the 512 float4 of a row: pos = k*64 + lane.
        // Per k: 4 h-loads (streaming, HBM) + 8 W-loads (hot in L1/L2),
        // 32 float4 FMAs. W traffic per token = 16 KB.
        #pragma unroll
        for (int k = 0; k < 8; k++) {
            float4 hv[4];
            #pragma unroll
            for (int t = 0; t < 4; t++)
                hv[t] = h4[(size_t)(t0 + t) * ROW_F4 + k * 64 + lane];
            #pragma unroll
            for (int e = 0; e < N_EXPERTS; e++) {
                float4 wv = w4[e * ROW_F4 + k * 64 + lane];
                #pragma unroll
                for (int t = 0; t < 4; t++)
                    acc[t][e] += hv[t].x * wv.x + hv[t].y * wv.y
                               + hv[t].z * wv.z + hv[t].w * wv.w;
            }
        }

        // 64-lane shuffle reduction for all 32 accumulators
        #pragma unroll
        for (int t = 0; t < 4; t++)
            #pragma unroll
            for (int e = 0; e < N_EXPERTS; e++)
                #pragma unroll
                for (int off = 32; off > 0; off >>= 1)
                    acc[t][e] += __shfl_down(acc[t][e], off, 64);

        if (lane == 0) {
            #pragma unroll
            for (int t = 0; t < 4; t++) {
                const int tok = t0 + t;
                // top-2 of 8; strict > keeps first index on ties (== lax.top_k)
                int i1 = 0; float v1 = acc[t][0];
                #pragma unroll
                for (int e = 1; e < N_EXPERTS; e++)
                    if (acc[t][e] > v1) { v1 = acc[t][e]; i1 = e; }
                int i2 = -1; float v2 = -INFINITY;
                #pragma unroll
                for (int e = 0; e < N_EXPERTS; e++)
                    if (e != i1 && acc[t][e] > v2) { v2 = acc[t][e]; i2 = e; }

                float s1 = 1.f / (1.f + expf(-v1));
                float s2 = 1.f / (1.f + expf(-v2));

                #pragma unroll
                for (int e = 0; e < N_EXPERTS; e++) {
                    float val = (e == i1) ? s1 : ((e == i2) ? s2 : 0.f);
                    out0[e * T_TOKENS + tok] = val;
                    out2[e * T_TOKENS + tok] = val;
                }
            }
        }
    } else {
        // ------------------- fill role: stream router_indices -------------------
        // Row er = e*T + t holds constant value t = er & 4095 across H=2048.
        // One wave covers a row as 8 unrolled 1 KB wave-wide dwordx4 stores;
        // v is computed once per 8 KB row. Plain stores (NT was 6x slower, R2).
        const int fb    = bid - ROUTER_BLOCKS;             // 0..1791
        const int fwave = fb * 4 + wave;                   // 0..7167
        float4* o4 = (float4*)out1;

        for (int r = fwave; r < N_ROWS; r += FILL_WAVES) {
            float v = (float)(r & (T_TOKENS - 1));
            float4 vv = make_float4(v, v, v, v);
            float4* rowp = o4 + (size_t)r * ROW_F4;
            #pragma unroll
            for (int j = 0; j < 8; j++)
                rowp[j * 64 + lane] = vv;
        }
    }
}

extern "C" void kernel_launch(void* const* d_in, const int* in_sizes, int n_in,
                              void* d_out, int out_size, void* d_ws, size_t ws_size,
                              hipStream_t stream) {
    const float* h = (const float*)d_in[0];   // [4096, 2048] f32
    const float* w = (const float*)d_in[1];   // [8, 2048] f32
    // d_in[2] = top_k (always 2 for this problem)

    float* out  = (float*)d_out;
    float* out0 = out;                                            // router_scores [8,4096]
    float* out1 = out + N_EXPERTS * T_TOKENS;                     // router_indices [32768,2048]
    float* out2 = out1 + (size_t)N_EXPERTS * T_TOKENS * HIDDEN;   // router_probs [32768,1]

    hipLaunchKernelGGL(fused_router_fill, dim3(NBLOCKS), dim3(256), 0, stream,
                       h, w, out0, out1, out2);
}

// Round 3
// 302.228 us; speedup vs baseline: 1.2087x; 1.1005x over previous
//
#include <hip/hip_runtime.h>
#include <math.h>

#define T_TOKENS 4096
#define HIDDEN   2048
#define N_EXPERTS 8
#define N_ROWS   (N_EXPERTS * T_TOKENS)   // 32768 rows of router_indices
#define ROW_F4   (HIDDEN / 4)             // 512 float4 per row

// R5 geometry: 2048 blocks x 256 (8192 waves), 0 LDS.
//  - EVERY wave fills 4 contiguous rows of router_indices (8192*4 = 32768).
//  - Waves with gw < 4096 additionally compute the router for token t = gw
//    (1 token/wave). These are blocks 0..1023 -> round-robin over all XCDs
//    and CUs: ~16 router waves per CU instead of 4 (R2's tail problem).
//  - Per router wave, program order is: issue all 8 h-row loads (oldest in
//    vmcnt), then the 32 fill stores (no dependency -> fills the latency
//    shadow), then W loads + FMA (W is 64 KB, L2-hot). The s_waitcnt before
//    the first FMA only needs the 8 oldest entries, not the stores.
// R2 post-mortem: router work confined to 4 waves/CU was latency-bound
// (Occupancy 16%, VALUBusy 2.4%, ~144 us); fill waves exited early.
#define NBLOCKS 2048

__global__ __launch_bounds__(256) void fused_router_fill(
    const float* __restrict__ h, const float* __restrict__ w,
    float* __restrict__ out0, float* __restrict__ out1, float* __restrict__ out2)
{
    const int wave = threadIdx.x >> 6;
    const int lane = threadIdx.x & 63;
    const int gw   = blockIdx.x * 4 + wave;     // global wave id, 0..8191
    const bool is_router = (gw < T_TOKENS);

    const float4* h4 = (const float4*)h;
    const float4* w4 = (const float4*)w;

    // ---- 1. issue the whole 8 KB token row (8 independent 1 KB loads) ----
    float4 hv[8];
    if (is_router) {
        #pragma unroll
        for (int j = 0; j < 8; j++)
            hv[j] = h4[(size_t)gw * ROW_F4 + j * 64 + lane];
    }

    // ---- 2. fill role: 4 contiguous rows (32 KB of stores), all waves ----
    {
        float4* o4 = (float4*)out1;
        const int r0 = gw * 4;
        #pragma unroll
        for (int i = 0; i < 4; i++) {
            float v = (float)((r0 + i) & (T_TOKENS - 1));
            float4 vv = make_float4(v, v, v, v);
            float4* rowp = o4 + (size_t)(r0 + i) * ROW_F4;
            #pragma unroll
            for (int j = 0; j < 8; j++)
                rowp[j * 64 + lane] = vv;
        }
    }

    // ---- 3. router role: 8 expert dots + reduce + top-2 + sigmoid ----
    if (is_router) {
        float acc[N_EXPERTS];
        #pragma unroll
        for (int e = 0; e < N_EXPERTS; e++) acc[e] = 0.f;

        #pragma unroll
        for (int e = 0; e < N_EXPERTS; e++) {
            #pragma unroll
            for (int j = 0; j < 8; j++) {
                float4 wv = w4[e * ROW_F4 + j * 64 + lane];
                acc[e] += hv[j].x * wv.x + hv[j].y * wv.y
                        + hv[j].z * wv.z + hv[j].w * wv.w;
            }
        }

        // 64-lane shuffle reduction per expert
        #pragma unroll
        for (int e = 0; e < N_EXPERTS; e++) {
            #pragma unroll
            for (int off = 32; off > 0; off >>= 1)
                acc[e] += __shfl_down(acc[e], off, 64);
        }

        if (lane == 0) {
            // top-2 of 8; strict > keeps first index on ties (== lax.top_k)
            int i1 = 0; float v1 = acc[0];
            #pragma unroll
            for (int e = 1; e < N_EXPERTS; e++)
                if (acc[e] > v1) { v1 = acc[e]; i1 = e; }
            int i2 = -1; float v2 = -INFINITY;
            #pragma unroll
            for (int e = 0; e < N_EXPERTS; e++)
                if (e != i1 && acc[e] > v2) { v2 = acc[e]; i2 = e; }

            float s1 = 1.f / (1.f + expf(-v1));
            float s2 = 1.f / (1.f + expf(-v2));

            #pragma unroll
            for (int e = 0; e < N_EXPERTS; e++) {
                float val = (e == i1) ? s1 : ((e == i2) ? s2 : 0.f);
                out0[e * T_TOKENS + gw] = val;
                out2[e * T_TOKENS + gw] = val;
            }
        }
    }
}

extern "C" void kernel_launch(void* const* d_in, const int* in_sizes, int n_in,
                              void* d_out, int out_size, void* d_ws, size_t ws_size,
                              hipStream_t stream) {
    const float* h = (const float*)d_in[0];   // [4096, 2048] f32
    const float* w = (const float*)d_in[1];   // [8, 2048] f32
    // d_in[2] = top_k (always 2 for this problem)

    float* out  = (float*)d_out;
    float* out0 = out;                                            // router_scores [8,4096]
    float* out1 = out + N_EXPERTS * T_TOKENS;                     // router_indices [32768,2048]
    float* out2 = out1 + (size_t)N_EXPERTS * T_TOKENS * HIDDEN;   // router_probs [32768,1]

    hipLaunchKernelGGL(fused_router_fill, dim3(NBLOCKS), dim3(256), 0, stream,
                       h, w, out0, out1, out2);
}